// Round 1
// baseline (638.743 us; speedup 1.0000x reference)
//
#include <hip/hip_runtime.h>

typedef _Float16 f16;
typedef _Float16 f16x8 __attribute__((ext_vector_type(8)));
typedef _Float16 f16x4 __attribute__((ext_vector_type(4)));
typedef float    f32x4 __attribute__((ext_vector_type(4)));

#define NB 4
#define SEQ 4096
#define DIM 512
#define MTOT (NB*SEQ)   // 16384

// ---------------------------------------------------------------------------
// Projection GEMM: out[m,n] = f16( sum_k A[m,k] * W[n,k] + bias[n] )
// A: fp32 [16384,512], W: fp32 [512,512]; tile 128x128, BK=32, 4 waves.
// blockIdx.z selects projection: 0:q(x,Wq) 1:qv(x,Wqv) 2:k(y,Wk) 3:kv(y,Wkv)
// ---------------------------------------------------------------------------
__global__ __launch_bounds__(256) void proj_gemm(
    const float* __restrict__ x, const float* __restrict__ y,
    const float* __restrict__ Wq, const float* __restrict__ bq,
    const float* __restrict__ Wqv, const float* __restrict__ bqv,
    const float* __restrict__ Wk, const float* __restrict__ bk,
    const float* __restrict__ Wkv, const float* __restrict__ bkv,
    f16* __restrict__ qh, f16* __restrict__ qvh,
    f16* __restrict__ kh, f16* __restrict__ kvh)
{
    __shared__ __attribute__((aligned(16))) f16 a_lds[128][40]; // pad 32->40: 2-way max
    __shared__ __attribute__((aligned(16))) f16 b_lds[128][40];

    const int p = blockIdx.z;
    const float* A    = (p < 2) ? x : y;
    const float* W    = (p==0)?Wq:(p==1)?Wqv:(p==2)?Wk:Wkv;
    const float* bias = (p==0)?bq:(p==1)?bqv:(p==2)?bk:bkv;
    f16* out          = (p==0)?qh:(p==1)?qvh:(p==2)?kh:kvh;

    const int m0 = blockIdx.y * 128, n0 = blockIdx.x * 128;
    const int tid = threadIdx.x, lane = tid & 63, wv = tid >> 6;
    const int wm = wv >> 1, wn = wv & 1, mrow = lane & 15, qd = lane >> 4;

    f32x4 acc[4][4];
#pragma unroll
    for (int mt = 0; mt < 4; ++mt)
#pragma unroll
        for (int nt = 0; nt < 4; ++nt) acc[mt][nt] = (f32x4){0.f,0.f,0.f,0.f};

    float bv[4];
#pragma unroll
    for (int nt = 0; nt < 4; ++nt) bv[nt] = bias[n0 + wn*64 + nt*16 + mrow];

    for (int k0 = 0; k0 < DIM; k0 += 32) {
        __syncthreads();
#pragma unroll
        for (int i = 0; i < 4; ++i) {           // A tile 128x32 f32 -> f16 LDS
            int c = i*256 + tid;
            int row = c >> 3, c4 = c & 7;
            float4 v = *(const float4*)(A + (size_t)(m0+row)*DIM + k0 + c4*4);
            f16x4 h = { (f16)v.x, (f16)v.y, (f16)v.z, (f16)v.w };
            *(f16x4*)&a_lds[row][c4*4] = h;
        }
#pragma unroll
        for (int i = 0; i < 4; ++i) {           // W tile 128x32
            int c = i*256 + tid;
            int row = c >> 3, c4 = c & 7;
            float4 v = *(const float4*)(W + (size_t)(n0+row)*DIM + k0 + c4*4);
            f16x4 h = { (f16)v.x, (f16)v.y, (f16)v.z, (f16)v.w };
            *(f16x4*)&b_lds[row][c4*4] = h;
        }
        __syncthreads();
        f16x8 af[4], bfr[4];
#pragma unroll
        for (int mt = 0; mt < 4; ++mt) af[mt]  = *(const f16x8*)&a_lds[wm*64 + mt*16 + mrow][qd*8];
#pragma unroll
        for (int nt = 0; nt < 4; ++nt) bfr[nt] = *(const f16x8*)&b_lds[wn*64 + nt*16 + mrow][qd*8];
#pragma unroll
        for (int mt = 0; mt < 4; ++mt)
#pragma unroll
            for (int nt = 0; nt < 4; ++nt)
                acc[mt][nt] = __builtin_amdgcn_mfma_f32_16x16x32_f16(af[mt], bfr[nt], acc[mt][nt], 0,0,0);
    }
    // epilogue: C layout col=lane&15, row=4*(lane>>4)+reg
#pragma unroll
    for (int mt = 0; mt < 4; ++mt)
#pragma unroll
        for (int r = 0; r < 4; ++r) {
            size_t grow = (size_t)(m0 + wm*64 + mt*16 + qd*4 + r) * DIM;
#pragma unroll
            for (int nt = 0; nt < 4; ++nt) {
                int col = n0 + wn*64 + nt*16 + mrow;
                out[grow + col] = (f16)(acc[mt][nt][r] + bv[nt]);
            }
        }
}

// ---------------------------------------------------------------------------
// kv [B,S,D] -> kvT [B,D,S] (f16), 32x32 LDS tiles
// ---------------------------------------------------------------------------
__global__ void transpose_k(const f16* __restrict__ kvh, f16* __restrict__ kvT)
{
    __shared__ __attribute__((aligned(16))) f16 t[32][33];
    const int b = blockIdx.z;
    const int s0 = blockIdx.x * 32, d0 = blockIdx.y * 32;
    const int tx = threadIdx.x, ty = threadIdx.y;
#pragma unroll
    for (int i = 0; i < 4; ++i) {
        int r = ty + i*8;
        t[r][tx] = kvh[(size_t)(b*SEQ + s0 + r)*DIM + d0 + tx];
    }
    __syncthreads();
#pragma unroll
    for (int i = 0; i < 4; ++i) {
        int r = ty + i*8;
        kvT[(size_t)(b*DIM + d0 + r)*SEQ + s0 + tx] = t[tx][r];
    }
}

// ---------------------------------------------------------------------------
// Flash attention: per wg (128 thr, 2 waves) one 32-row Q tile of one batch.
// Each wave: 16 q-rows. kv-tile = 32 rows, 128 iterations over S=4096.
// ao[row] = softmax(q@K^T)[row] @ KV + qv[row]   (f16 out)
// ---------------------------------------------------------------------------
__global__ __launch_bounds__(128, 1) void attn_kernel(
    const f16* __restrict__ qh, const f16* __restrict__ kh,
    const f16* __restrict__ kvT, const f16* __restrict__ qvh,
    f16* __restrict__ ao)
{
    __shared__ __attribute__((aligned(16))) f16 k_lds[32][520];   // 33.3 KB, 2-way banks
    __shared__ __attribute__((aligned(16))) f16 kvt_lds[512][40]; // 41 KB, conflict-free reads
    __shared__ __attribute__((aligned(16))) f16 p_lds[2][16][40]; // per-wave P exchange

    const int bx = blockIdx.x;
    const int b  = bx >> 7;      // 128 q-tiles per batch
    const int qt = bx & 127;
    const int tid = threadIdx.x, lane = tid & 63, w = tid >> 6;
    const int mrow = lane & 15, qd = lane >> 4;

    // Q fragments, A-layout: lane m+16q holds Q[m][32*ks + 8q + j]
    const size_t qrow = (size_t)(b*SEQ + qt*32 + w*16 + mrow) * DIM;
    f16x8 qf[16];
#pragma unroll
    for (int ks = 0; ks < 16; ++ks)
        qf[ks] = *(const f16x8*)(qh + qrow + ks*32 + qd*8);

    f32x4 o[32];
#pragma unroll
    for (int nt = 0; nt < 32; ++nt) o[nt] = (f32x4){0.f,0.f,0.f,0.f};
    float m_i[4] = {-INFINITY,-INFINITY,-INFINITY,-INFINITY};
    float l_i[4] = {0.f,0.f,0.f,0.f};

    for (int it = 0; it < 128; ++it) {
        const int kk0 = it * 32;
        __syncthreads();
        // stage K tile 32x512 (rows of K, row-major -> B-frag for Q@K^T)
#pragma unroll
        for (int i = 0; i < 16; ++i) {
            int c = i*128 + tid;
            int row = c >> 6, c8 = c & 63;
            *(f16x8*)&k_lds[row][c8*8] =
                *(const f16x8*)(kh + (size_t)(b*SEQ + kk0 + row)*DIM + c8*8);
        }
        // stage KV^T tile 512x32 (rows of kvT -> B-frag for P@KV)
#pragma unroll
        for (int i = 0; i < 16; ++i) {
            int c = i*128 + tid;
            int d = c >> 2, c8 = c & 3;
            *(f16x8*)&kvt_lds[d][c8*8] =
                *(const f16x8*)(kvT + (size_t)(b*DIM + d)*SEQ + kk0 + c8*8);
        }
        __syncthreads();

        // S = Q @ K^T : 16x32 per wave (2 n-tiles)
        f32x4 s0 = (f32x4){0.f,0.f,0.f,0.f}, s1 = s0;
#pragma unroll
        for (int ks = 0; ks < 16; ++ks) {
            f16x8 kf0 = *(const f16x8*)&k_lds[mrow][ks*32 + qd*8];
            f16x8 kf1 = *(const f16x8*)&k_lds[16 + mrow][ks*32 + qd*8];
            s0 = __builtin_amdgcn_mfma_f32_16x16x32_f16(qf[ks], kf0, s0, 0,0,0);
            s1 = __builtin_amdgcn_mfma_f32_16x16x32_f16(qf[ks], kf1, s1, 0,0,0);
        }

        // online softmax: row r=4*qd+reg held by the 16 lanes of quad qd
        float alpha[4];
        bool changed = false;
#pragma unroll
        for (int r = 0; r < 4; ++r) {
            float v = fmaxf(s0[r], s1[r]);
            v = fmaxf(v, __shfl_xor(v, 1));
            v = fmaxf(v, __shfl_xor(v, 2));
            v = fmaxf(v, __shfl_xor(v, 4));
            v = fmaxf(v, __shfl_xor(v, 8));
            float mn = fmaxf(m_i[r], v);
            alpha[r] = __expf(m_i[r] - mn);
            if (mn > m_i[r]) changed = true;
            m_i[r] = mn;
            float p0 = __expf(s0[r] - mn);
            float p1 = __expf(s1[r] - mn);
            float rs = p0 + p1;
            rs += __shfl_xor(rs, 1);
            rs += __shfl_xor(rs, 2);
            rs += __shfl_xor(rs, 4);
            rs += __shfl_xor(rs, 8);
            l_i[r] = l_i[r]*alpha[r] + rs;
            s0[r] = p0; s1[r] = p1;
        }
        if (__any(changed)) {   // sharp softmax: max changes ~5/128 iters
#pragma unroll
            for (int nt = 0; nt < 32; ++nt)
#pragma unroll
                for (int r = 0; r < 4; ++r) o[nt][r] *= alpha[r];
        }

        // P: C-layout -> A-layout via per-wave LDS (intra-wave DS is in-order)
#pragma unroll
        for (int r = 0; r < 4; ++r) {
            p_lds[w][qd*4 + r][mrow]      = (f16)s0[r];
            p_lds[w][qd*4 + r][16 + mrow] = (f16)s1[r];
        }
        f16x8 pf = *(const f16x8*)&p_lds[w][mrow][qd*8];

        // O += P @ KV : 32 n-tiles of 16 cols
#pragma unroll
        for (int nt = 0; nt < 32; ++nt) {
            f16x8 kv = *(const f16x8*)&kvt_lds[nt*16 + mrow][qd*8];
            o[nt] = __builtin_amdgcn_mfma_f32_16x16x32_f16(pf, kv, o[nt], 0,0,0);
        }
    }

    // epilogue: O/l + qv
    float inv_l[4];
#pragma unroll
    for (int r = 0; r < 4; ++r) inv_l[r] = 1.f / l_i[r];
#pragma unroll
    for (int r = 0; r < 4; ++r) {
        size_t grow = (size_t)(b*SEQ + qt*32 + w*16 + qd*4 + r) * DIM;
#pragma unroll
        for (int nt = 0; nt < 32; ++nt) {
            int col = nt*16 + mrow;
            float val = o[nt][r] * inv_l[r] + (float)qvh[grow + col];
            ao[grow + col] = (f16)val;
        }
    }
}

// ---------------------------------------------------------------------------
// Final linear: out[m,n] = sum_k ao[m,k]*Wf[n,k] + bf[n]  (f32 out)
// ---------------------------------------------------------------------------
__global__ __launch_bounds__(256) void final_gemm(
    const f16* __restrict__ ao, const float* __restrict__ Wf,
    const float* __restrict__ bf, float* __restrict__ out)
{
    __shared__ __attribute__((aligned(16))) f16 a_lds[128][40];
    __shared__ __attribute__((aligned(16))) f16 b_lds[128][40];

    const int m0 = blockIdx.y * 128, n0 = blockIdx.x * 128;
    const int tid = threadIdx.x, lane = tid & 63, wv = tid >> 6;
    const int wm = wv >> 1, wn = wv & 1, mrow = lane & 15, qd = lane >> 4;

    f32x4 acc[4][4];
#pragma unroll
    for (int mt = 0; mt < 4; ++mt)
#pragma unroll
        for (int nt = 0; nt < 4; ++nt) acc[mt][nt] = (f32x4){0.f,0.f,0.f,0.f};

    float bv[4];
#pragma unroll
    for (int nt = 0; nt < 4; ++nt) bv[nt] = bf[n0 + wn*64 + nt*16 + mrow];

    for (int k0 = 0; k0 < DIM; k0 += 32) {
        __syncthreads();
#pragma unroll
        for (int i = 0; i < 2; ++i) {           // A tile already f16: 512 chunks
            int c = i*256 + tid;
            int row = c >> 2, c8 = c & 3;
            *(f16x8*)&a_lds[row][c8*8] =
                *(const f16x8*)(ao + (size_t)(m0+row)*DIM + k0 + c8*8);
        }
#pragma unroll
        for (int i = 0; i < 4; ++i) {           // Wf tile f32 -> f16
            int c = i*256 + tid;
            int row = c >> 3, c4 = c & 7;
            float4 v = *(const float4*)(Wf + (size_t)(n0+row)*DIM + k0 + c4*4);
            f16x4 h = { (f16)v.x, (f16)v.y, (f16)v.z, (f16)v.w };
            *(f16x4*)&b_lds[row][c4*4] = h;
        }
        __syncthreads();
        f16x8 af[4], bfr[4];
#pragma unroll
        for (int mt = 0; mt < 4; ++mt) af[mt]  = *(const f16x8*)&a_lds[wm*64 + mt*16 + mrow][qd*8];
#pragma unroll
        for (int nt = 0; nt < 4; ++nt) bfr[nt] = *(const f16x8*)&b_lds[wn*64 + nt*16 + mrow][qd*8];
#pragma unroll
        for (int mt = 0; mt < 4; ++mt)
#pragma unroll
            for (int nt = 0; nt < 4; ++nt)
                acc[mt][nt] = __builtin_amdgcn_mfma_f32_16x16x32_f16(af[mt], bfr[nt], acc[mt][nt], 0,0,0);
    }
#pragma unroll
    for (int mt = 0; mt < 4; ++mt)
#pragma unroll
        for (int r = 0; r < 4; ++r) {
            size_t grow = (size_t)(m0 + wm*64 + mt*16 + qd*4 + r) * DIM;
#pragma unroll
            for (int nt = 0; nt < 4; ++nt) {
                int col = n0 + wn*64 + nt*16 + mrow;
                out[grow + col] = acc[mt][nt][r] + bv[nt];
            }
        }
}

// ---------------------------------------------------------------------------
extern "C" void kernel_launch(void* const* d_in, const int* in_sizes, int n_in,
                              void* d_out, int out_size, void* d_ws, size_t ws_size,
                              hipStream_t stream)
{
    const float* x   = (const float*)d_in[0];
    const float* y   = (const float*)d_in[1];
    const float* Wq  = (const float*)d_in[2];
    const float* bq  = (const float*)d_in[3];
    const float* Wqv = (const float*)d_in[4];
    const float* bqv = (const float*)d_in[5];
    const float* Wk  = (const float*)d_in[6];
    const float* bk  = (const float*)d_in[7];
    const float* Wkv = (const float*)d_in[8];
    const float* bkv = (const float*)d_in[9];
    const float* Wf  = (const float*)d_in[10];
    const float* bf  = (const float*)d_in[11];
    float* out = (float*)d_out;

    const size_t NE = (size_t)MTOT * DIM;
    f16* qh  = (f16*)d_ws;       // 16.8 MB each; 100.7 MB total
    f16* qvh = qh  + NE;
    f16* kh  = qvh + NE;
    f16* kvh = kh  + NE;
    f16* kvT = kvh + NE;
    f16* aob = kvT + NE;

    proj_gemm<<<dim3(4, 128, 4), 256, 0, stream>>>(
        x, y, Wq, bq, Wqv, bqv, Wk, bk, Wkv, bkv, qh, qvh, kh, kvh);
    transpose_k<<<dim3(128, 16, 4), dim3(32, 8), 0, stream>>>(kvh, kvT);
    attn_kernel<<<dim3(512), 128, 0, stream>>>(qh, kh, kvT, qvh, aob);
    final_gemm<<<dim3(4, 128), 256, 0, stream>>>(aob, Wf, bf, out);
}